// Round 9
// baseline (7605.959 us; speedup 1.0000x reference)
//
#include <hip/hip_runtime.h>
#include <hip/hip_bf16.h>
#include <cstdint>
#include <cstddef>

typedef unsigned short u16;
typedef unsigned int   u32;

typedef short s16x8 __attribute__((ext_vector_type(8)));
typedef float f32x4 __attribute__((ext_vector_type(4)));

__device__ __forceinline__ float b2f(u16 u){ u32 x = ((u32)u)<<16; float f; __builtin_memcpy(&f,&x,4); return f; }
__device__ __forceinline__ u16  f2b(float f){ u32 x; __builtin_memcpy(&x,&f,4); u32 r = x + 0x7FFFu + ((x>>16)&1u); return (u16)(r>>16); }

__device__ __forceinline__ void unpack8(uint4 v, float* o){
  o[0]=b2f((u16)v.x); o[1]=b2f((u16)(v.x>>16));
  o[2]=b2f((u16)v.y); o[3]=b2f((u16)(v.y>>16));
  o[4]=b2f((u16)v.z); o[5]=b2f((u16)(v.z>>16));
  o[6]=b2f((u16)v.w); o[7]=b2f((u16)(v.w>>16));
}

__device__ __forceinline__ void gl_lds16(const u16* g, u16* l){
  __builtin_amdgcn_global_load_lds((const __attribute__((address_space(1))) u32*)g,
                                   (__attribute__((address_space(3))) u32*)l, 16, 0, 0);
}

// ---------------- dtype detect ----------------
__global__ void k_detect(const u16* __restrict__ lnw, int* __restrict__ flag){
  if (threadIdx.x==0 && blockIdx.x==0) *flag = (lnw[0] == 0x3F80) ? 1 : 0;
}

// ---------------- zero lookback flags + tickets (re-poison safe, runs every launch) ----------------
__global__ void k_zero(u32* __restrict__ p){
  for (int i = threadIdx.x; i < 8196; i += 256) p[i] = 0u;
}

// ---------------- convert weights to canonical bf16 ----------------
struct CvtTable { const void* src[14]; u16* dst[14]; int n[14]; };
__global__ void k_cvt(CvtTable t, const int* __restrict__ flag){
  int ti = blockIdx.y;
  int n = t.n[ti];
  int isbf = *flag;
  const u16*  sb = (const u16*)t.src[ti];
  const float* sf = (const float*)t.src[ti];
  u16* d = t.dst[ti];
  for (int i = blockIdx.x*256 + threadIdx.x; i < n; i += gridDim.x*256)
    d[i] = isbf ? sb[i] : f2b(sf[i]);
}

// ---------------- segment mean ----------------
__global__ void k_mean(const void* __restrict__ data, const int* __restrict__ rl,
                       float* __restrict__ x, const int* __restrict__ flag){
  __shared__ float tile[32][129];
  int isbf = *flag;
  const u16*  db = (const u16*)data;
  const float* df_ = (const float*)data;
  int g = blockIdx.z, c0 = blockIdx.y*32, l0 = blockIdx.x*128;
  int tid = threadIdx.x;
  int off=0; for(int i=0;i<g;i++) off += rl[i];
  int cnt = rl[g];
  float inv = 1.0f/(float)cnt;
  for(int it=0; it<16; ++it){
    int idx = it*256 + tid;
    int ci = idx>>7, lj = idx&127;
    float acc = 0.f;
    for(int b=0;b<cnt;b++){
      size_t gi = ((size_t)(off+b)*256 + (c0+ci)) * 4096 + (l0+lj);
      acc += isbf ? b2f(db[gi]) : df_[gi];
    }
    tile[ci][lj] = acc*inv;
  }
  __syncthreads();
  for(int it=0; it<16; ++it){
    int idx = it*256 + tid;
    int lj = idx>>5, ci = idx&31;
    x[ ((size_t)g*4096 + (l0+lj))*256 + (c0+ci) ] = tile[ci][lj];
  }
}

// ---------------- Bcomb prep ----------------
__global__ void k_prep(const u16* __restrict__ dtp, const u16* __restrict__ xpw, u16* __restrict__ bcomb){
  int layer = blockIdx.y, row = blockIdx.x, c = threadIdx.x;
  u16 out;
  if (row < 256){
    float acc = 0.f;
    #pragma unroll
    for(int r=0;r<16;r++)
      acc += b2f(dtp[(size_t)layer*4096 + row*16 + r]) * b2f(xpw[(size_t)layer*8192 + r*256 + c]);
    out = f2b(acc);
  } else if (row < 272){
    out = xpw[(size_t)layer*8192 + (16 + row - 256)*256 + c];
  } else {
    out = 0;
  }
  bcomb[((size_t)layer*384 + row)*256 + c] = out;
}

// ---------------- LN1 (layer 0 only), hi/lo split output ----------------
__global__ void k_ln1(const float* __restrict__ x, u16* __restrict__ xnh, u16* __restrict__ xnl,
                      const u16* __restrict__ w, const u16* __restrict__ b, int layer){
  int wid = threadIdx.x>>6, lane = threadIdx.x&63;
  int row = blockIdx.x*4 + wid;
  const float* xr = x + (size_t)row*256;
  float4 v = *(const float4*)(xr + lane*4);
  float s = v.x+v.y+v.z+v.w;
  float q = v.x*v.x+v.y*v.y+v.z*v.z+v.w*v.w;
  for(int o=32;o;o>>=1){ s += __shfl_xor(s,o); q += __shfl_xor(q,o); }
  float mu = s*(1.f/256.f);
  float var = q*(1.f/256.f) - mu*mu;
  float rs = rsqrtf(var + 1e-5f);
  const u16* wp = w + layer*256 + lane*4;
  const u16* bp = b + layer*256 + lane*4;
  float vv[4] = {v.x,v.y,v.z,v.w};
  u16 h4[4], l4[4];
  #pragma unroll
  for(int k2=0;k2<4;k2++){
    float xv = (vv[k2]-mu)*rs*b2f(wp[k2]) + b2f(bp[k2]);
    h4[k2] = f2b(xv);
    l4[k2] = f2b(xv - b2f(h4[k2]));
  }
  uint2 oh; oh.x = (u32)h4[0] | ((u32)h4[1]<<16); oh.y = (u32)h4[2] | ((u32)h4[3]<<16);
  uint2 ol; ol.x = (u32)l4[0] | ((u32)l4[1]<<16); ol.y = (u32)l4[2] | ((u32)l4[3]<<16);
  *(uint2*)(xnh + (size_t)row*256 + lane*4) = oh;
  *(uint2*)(xnl + (size_t)row*256 + lane*4) = ol;
}

// ---------------- bf16 NT GEMM, 128x128 tile, BK=64, K=256, XOR-swizzled LDS ----------------
// MODE 0: split-A (hi+lo) in_proj: n<256 -> x fp32 (C0f, ld 256), n>=256 -> z bf16 (C1)
// MODE 1: single-A x_proj/delta: softplus+bias -> C0 bf16, raw B/C rows -> C1 bf16
template<int MODE>
__global__ __launch_bounds__(256)
void k_gemm(const u16* __restrict__ A, const u16* __restrict__ Alo,
            const u16* __restrict__ B,
            u16* __restrict__ C0, float* __restrict__ C0f, int ldC,
            const u16* __restrict__ bias, u16* __restrict__ C1){
  __shared__ u16 As[128*64];
  __shared__ u16 Bs[128*64];
  __shared__ u16 Asl[(MODE==0)?(128*64):16];
  int tid = threadIdx.x, wid = tid>>6, lane = tid&63;
  int m0 = blockIdx.x*128, n0 = blockIdx.y*128;
  f32x4 acc[4][4];
  #pragma unroll
  for(int i=0;i<4;i++)
    #pragma unroll
    for(int j=0;j<4;j++) acc[i][j] = (f32x4){0.f,0.f,0.f,0.f};
  int lrow  = lane>>3;
  int scol  = ((lane&7) ^ lrow) * 8;
  int rm = (wid&1)*64, cn = (wid>>1)*64;
  for(int k0=0;k0<256;k0+=64){
    #pragma unroll
    for(int it=0; it<4; ++it){
      int chunk = wid*4 + it;
      int row = chunk*8 + lrow;
      gl_lds16(A + (size_t)(m0+row)*256 + k0 + scol, As + chunk*512 + lane*8);
      if (MODE==0)
        gl_lds16(Alo + (size_t)(m0+row)*256 + k0 + scol, Asl + chunk*512 + lane*8);
      gl_lds16(B + (size_t)(n0+row)*256 + k0 + scol, Bs + chunk*512 + lane*8);
    }
    __syncthreads();
    #pragma unroll
    for(int kk=0;kk<2;kk++){
      s16x8 af[4], afl[4], bfr[4];
      #pragma unroll
      for(int i=0;i<4;i++){
        int ar = rm + i*16 + (lane&15);
        int ap = (kk*4 + (lane>>4)) ^ (ar&7);
        af[i]  = *(const s16x8*)(As + ar*64 + ap*8);
        if (MODE==0) afl[i] = *(const s16x8*)(Asl + ar*64 + ap*8);
        int br = cn + i*16 + (lane&15);
        int bp = (kk*4 + (lane>>4)) ^ (br&7);
        bfr[i] = *(const s16x8*)(Bs + br*64 + bp*8);
      }
      #pragma unroll
      for(int i=0;i<4;i++)
        #pragma unroll
        for(int j=0;j<4;j++){
          acc[i][j] = __builtin_amdgcn_mfma_f32_16x16x32_bf16(af[i], bfr[j], acc[i][j], 0,0,0);
          if (MODE==0)
            acc[i][j] = __builtin_amdgcn_mfma_f32_16x16x32_bf16(afl[i], bfr[j], acc[i][j], 0,0,0);
        }
    }
    __syncthreads();
  }
  #pragma unroll
  for(int i=0;i<4;i++){
    #pragma unroll
    for(int j=0;j<4;j++){
      int n  = n0 + cn + j*16 + (lane&15);
      int mB = m0 + rm + i*16 + ((lane>>4)<<2);
      #pragma unroll
      for(int r=0;r<4;r++){
        float val = acc[i][j][r];
        int m = mB + r;
        if (MODE==0){
          if (n < 256) C0f[(size_t)m*256 + n] = val;
          else         C1[(size_t)m*256 + (n-256)] = f2b(val);
        } else {
          if (n < 256){
            float v2 = val + b2f(bias[n]);
            float sp = (v2 > 15.f) ? v2 : __logf(1.f + __expf(v2));
            C0[(size_t)m*256 + n] = f2b(sp);
          } else if (n < 272){
            C1[(size_t)m*16 + (n-256)] = f2b(val);
          }
        }
      }
    }
  }
}

// ---------------- depthwise conv + SiLU from fp32 x (g,l,256), 32 positions per block ----------------
__global__ void k_conv(const float* __restrict__ xf, const u16* __restrict__ cw,
                       const u16* __restrict__ cb, u16* __restrict__ xcf, u16* __restrict__ xcb_, int layer){
  int l0 = blockIdx.x*32, g = blockIdx.y, d = threadIdx.x;
  float w[4];
  #pragma unroll
  for(int j=0;j<4;j++) w[j] = b2f(cw[(size_t)layer*1024 + d*4 + j]);
  float bb = b2f(cb[layer*256 + d]);
  float xv[38];
  #pragma unroll
  for(int t=0;t<38;t++){
    int lp = l0 - 3 + t;
    xv[t] = (lp>=0 && lp<4096) ? xf[((size_t)g*4096 + lp)*256 + d] : 0.f;
  }
  #pragma unroll
  for(int i=0;i<32;i++){
    float af = bb, ab = bb;
    #pragma unroll
    for(int j=0;j<4;j++){ af += w[j]*xv[i+j]; ab += w[j]*xv[i+6-j]; }
    af = af / (1.f + __expf(-af));
    ab = ab / (1.f + __expf(-ab));
    size_t o = ((size_t)g*4096 + (l0+i))*256 + d;
    xcf[o]  = f2b(af);
    xcb_[o] = f2b(ab);
  }
}

// ---------------- single-pass scan with decoupled lookback (replaces scan1+scan2+scanY) ----------------
// ticket t -> gd = t&15 (dir= gd>>3, g = gd&7), c = t>>4 (chunk in scan order).
// Lower tickets never wait on higher tickets -> deadlock-free under any dispatch order.
__global__ __launch_bounds__(256)
void k_scanlb(const u16* __restrict__ df, const u16* __restrict__ db,
              const u16* __restrict__ uf, const u16* __restrict__ ub,
              const u16* __restrict__ bcf, const u16* __restrict__ bcb,
              const float* __restrict__ xf,
              const u16* __restrict__ Alog, const u16* __restrict__ Ablog,
              const u16* __restrict__ Dp, const u16* __restrict__ cw, const u16* __restrict__ cbp,
              float* __restrict__ aga, float* __restrict__ agb, float* __restrict__ hinc,
              u32* __restrict__ flags, u32* __restrict__ ticket,
              float* __restrict__ yf, float* __restrict__ yb, int layer){
  __shared__ u32 s_t;
  if (threadIdx.x==0) s_t = atomicAdd(ticket + layer, 1u);
  __syncthreads();
  int gd = (int)(s_t & 15u), c = (int)(s_t >> 4);
  int dir = gd >> 3, g = gd & 7;
  int d = threadIdx.x;
  const u16* dl = dir ? db : df;
  const u16* uu = dir ? ub : uf;
  const u16* bc = dir ? bcb : bcf;
  const u16* Al = dir ? Ablog : Alog;
  float An[8], h[8], ap[8];
  #pragma unroll
  for(int n=0;n<8;n++){
    An[n] = -__expf(b2f(Al[(size_t)layer*2048 + d*8 + n]));
    h[n] = 0.f; ap[n] = 1.f;
  }
  // ---- pass 1: chunk aggregate (bf16 u from XCF/XCB; identical numerics to old scan1) ----
  #pragma unroll 4
  for(int t=0;t<32;t++){
    int ts = c*32 + t;
    int tg = dir ? (4095 - ts) : ts;
    size_t rowo = (size_t)g*4096 + tg;
    float dv = b2f(dl[rowo*256 + d]);
    float uv = b2f(uu[rowo*256 + d]);
    uint4 bv = *(const uint4*)(bc + rowo*16);
    float bn[8]; unpack8(bv, bn);
    float du = dv*uv;
    #pragma unroll
    for(int n=0;n<8;n++){
      float da = __expf(dv*An[n]);
      h[n] = fmaf(da, h[n], du*bn[n]);
      ap[n] *= da;
    }
  }
  size_t pb = (((size_t)gd)*128 + c)*2048 + (size_t)d*8;
  *(float4*)(aga+pb)   = (float4){ap[0],ap[1],ap[2],ap[3]};
  *(float4*)(aga+pb+4) = (float4){ap[4],ap[5],ap[6],ap[7]};
  *(float4*)(agb+pb)   = (float4){h[0],h[1],h[2],h[3]};
  *(float4*)(agb+pb+4) = (float4){h[4],h[5],h[6],h[7]};
  __threadfence();
  __syncthreads();
  u32* flg = flags + ((size_t)layer*16 + gd)*128;
  if (threadIdx.x==0)
    __hip_atomic_store(&flg[c], 1u, __ATOMIC_RELEASE, __HIP_MEMORY_SCOPE_AGENT);
  // ---- lookback: compose predecessor transforms (Horner order = old scan2 association) ----
  float h0[8];
  #pragma unroll
  for(int n=0;n<8;n++) h0[n] = 0.f;
  if (c > 0){
    float TA[8], TB[8];
    #pragma unroll
    for(int n=0;n<8;n++){ TA[n]=1.f; TB[n]=0.f; }
    int p = c-1;
    while(true){
      u32 f;
      while ((f = __hip_atomic_load(&flg[p], __ATOMIC_ACQUIRE, __HIP_MEMORY_SCOPE_AGENT)) == 0u)
        __builtin_amdgcn_s_sleep(2);
      size_t qb = (((size_t)gd)*128 + p)*2048 + (size_t)d*8;
      if (f >= 2u){
        #pragma unroll
        for(int n=0;n<8;n++) h0[n] = fmaf(TA[n], hinc[qb+n], TB[n]);
        break;
      }
      #pragma unroll
      for(int n=0;n<8;n++){
        float Ap = aga[qb+n], Bp = agb[qb+n];
        TB[n] = fmaf(TA[n], Bp, TB[n]);
        TA[n] *= Ap;
      }
      if (--p < 0){
        #pragma unroll
        for(int n=0;n<8;n++) h0[n] = TB[n];
        break;
      }
    }
  }
  // ---- publish inclusive state ----
  #pragma unroll
  for(int n=0;n<8;n++) h[n] = fmaf(ap[n], h0[n], h[n]);
  *(float4*)(hinc+pb)   = (float4){h[0],h[1],h[2],h[3]};
  *(float4*)(hinc+pb+4) = (float4){h[4],h[5],h[6],h[7]};
  __threadfence();
  __syncthreads();
  if (threadIdx.x==0)
    __hip_atomic_store(&flg[c], 2u, __ATOMIC_RELEASE, __HIP_MEMORY_SCOPE_AGENT);
  // ---- pass 2: replay with fp32 on-the-fly conv u, from h0; write pre-gate y ----
  float w0 = b2f(cw[(size_t)layer*1024 + d*4 + 0]);
  float w1 = b2f(cw[(size_t)layer*1024 + d*4 + 1]);
  float w2 = b2f(cw[(size_t)layer*1024 + d*4 + 2]);
  float w3 = b2f(cw[(size_t)layer*1024 + d*4 + 3]);
  float cbb = b2f(cbp[layer*256 + d]);
  float Dd = b2f(Dp[layer*256 + d]);
  const float* xrow = xf + (size_t)g*4096*256 + d;
  #pragma unroll
  for(int n=0;n<8;n++) h[n] = h0[n];
  if (dir == 0){
    int l0 = c*32;
    float wm1 = (l0-1>=0) ? xrow[(size_t)(l0-1)*256] : 0.f;
    float wm2 = (l0-2>=0) ? xrow[(size_t)(l0-2)*256] : 0.f;
    float wm3 = (l0-3>=0) ? xrow[(size_t)(l0-3)*256] : 0.f;
    #pragma unroll 4
    for(int t=0;t<32;t++){
      size_t rowo = (size_t)g*4096 + l0 + t;
      float x0 = xrow[(size_t)(l0+t)*256];
      float ucv = cbb + w0*wm3 + w1*wm2 + w2*wm1 + w3*x0;
      wm3 = wm2; wm2 = wm1; wm1 = x0;
      float uv = ucv / (1.f + __expf(-ucv));
      float dv = b2f(df[rowo*256 + d]);
      uint4 bv = *(const uint4*)(bcf + rowo*16);
      uint4 cv = *(const uint4*)(bcf + rowo*16 + 8);
      float bn[8], cn_[8];
      unpack8(bv, bn); unpack8(cv, cn_);
      float du = dv*uv;
      float y = 0.f;
      #pragma unroll
      for(int n=0;n<8;n++){
        float da = __expf(dv*An[n]);
        h[n] = fmaf(da, h[n], du*bn[n]);
        y = fmaf(h[n], cn_[n], y);
      }
      yf[rowo*256 + d] = y + Dd*uv;
    }
  } else {
    int l0 = (127 - c)*32;
    float xw1 = (l0+32<4096) ? xrow[(size_t)(l0+32)*256] : 0.f;
    float xw2 = (l0+33<4096) ? xrow[(size_t)(l0+33)*256] : 0.f;
    float xw3 = (l0+34<4096) ? xrow[(size_t)(l0+34)*256] : 0.f;
    #pragma unroll 4
    for(int q=0;q<32;q++){
      int t = 31 - q;
      size_t rowo = (size_t)g*4096 + l0 + t;
      float x0 = xrow[(size_t)(l0+t)*256];
      float ucv = cbb + w3*x0 + w2*xw1 + w1*xw2 + w0*xw3;
      xw3 = xw2; xw2 = xw1; xw1 = x0;
      float uv = ucv / (1.f + __expf(-ucv));
      float dv = b2f(db[rowo*256 + d]);
      uint4 bv = *(const uint4*)(bcb + rowo*16);
      uint4 cv = *(const uint4*)(bcb + rowo*16 + 8);
      float bn[8], cn_[8];
      unpack8(bv, bn); unpack8(cv, cn_);
      float du = dv*uv;
      float y = 0.f;
      #pragma unroll
      for(int n=0;n<8;n++){
        float da = __expf(dv*An[n]);
        h[n] = fmaf(da, h[n], du*bn[n]);
        y = fmaf(h[n], cn_[n], y);
      }
      yb[rowo*256 + d] = y + Dd*uv;
    }
  }
}

// ---------------- out_proj GEMM: reg-staged A = 0.5*silu(z)*(yf+yb) -> bf16; + LN2 + residual (+ next LN1 hi/lo) ----------------
template<int LAST>
__global__ __launch_bounds__(256)
void k_outproj(const float* __restrict__ yf, const float* __restrict__ yb,
               const u16* __restrict__ zb,
               const u16* __restrict__ Bw,
               float* __restrict__ X, u16* __restrict__ xnh, u16* __restrict__ xnl,
               const u16* __restrict__ mnw, const u16* __restrict__ mnb,
               const u16* __restrict__ lnw_n, const u16* __restrict__ lnb_n){
  __shared__ u16 Ash[64*64];   // 8 KB
  __shared__ u16 Bs[256*64];   // 32 KB
  int tid = threadIdx.x, wid = tid>>6, lane = tid&63;
  int c = blockIdx.x, g = blockIdx.y;
  size_t row0 = (size_t)g*4096 + c*64;
  f32x4 acc[16];
  #pragma unroll
  for(int j=0;j<16;j++) acc[j] = (f32x4){0.f,0.f,0.f,0.f};
  int lrow = lane>>3;
  int scol = ((lane&7) ^ lrow) * 8;
  for(int k0=0;k0<256;k0+=64){
    #pragma unroll
    for(int it=0; it<2; ++it){
      int chunk = wid*2 + it;
      int row = chunk*8 + lrow;
      size_t off = (row0+row)*256 + k0 + scol;
      float4 a0 = *(const float4*)(yf+off);
      float4 a1 = *(const float4*)(yf+off+4);
      float4 b0 = *(const float4*)(yb+off);
      float4 b1 = *(const float4*)(yb+off+4);
      uint4 zv = *(const uint4*)(zb+off);
      float zs[8]; unpack8(zv, zs);
      float ys[8] = {a0.x+b0.x, a0.y+b0.y, a0.z+b0.z, a0.w+b0.w,
                     a1.x+b1.x, a1.y+b1.y, a1.z+b1.z, a1.w+b1.w};
      u16 o[8];
      #pragma unroll
      for(int j=0;j<8;j++){
        float yv = ys[j] * 0.5f * zs[j] / (1.f + __expf(-zs[j]));
        o[j] = f2b(yv);
      }
      uint4 ov;
      ov.x = (u32)o[0] | ((u32)o[1]<<16); ov.y = (u32)o[2] | ((u32)o[3]<<16);
      ov.z = (u32)o[4] | ((u32)o[5]<<16); ov.w = (u32)o[6] | ((u32)o[7]<<16);
      *(uint4*)(Ash + chunk*512 + lane*8) = ov;
    }
    #pragma unroll
    for(int it=0; it<8; ++it){
      int chunk = wid*8 + it;
      int row = chunk*8 + lrow;
      gl_lds16(Bw + (size_t)row*256 + k0 + scol, Bs + chunk*512 + lane*8);
    }
    __syncthreads();
    #pragma unroll
    for(int kk=0;kk<2;kk++){
      int ar = wid*16 + (lane&15);
      int q  = kk*4 + (lane>>4);
      s16x8 afh = *(const s16x8*)(Ash + ar*64 + (q^(ar&7))*8);
      #pragma unroll
      for(int j=0;j<16;j++){
        int br = j*16 + (lane&15);
        s16x8 bfv = *(const s16x8*)(Bs + br*64 + (q^(br&7))*8);
        acc[j] = __builtin_amdgcn_mfma_f32_16x16x32_bf16(afh, bfv, acc[j], 0,0,0);
      }
    }
    __syncthreads();
  }
  // ---- epilogue: LN2 + residual (+ next-layer LN1 hi/lo) ----
  size_t gm0 = row0;
  int quad = lane>>4;
  float sm[4]={0,0,0,0}, sq[4]={0,0,0,0};
  #pragma unroll
  for(int j=0;j<16;j++)
    #pragma unroll
    for(int r=0;r<4;r++){ float v=acc[j][r]; sm[r]+=v; sq[r]+=v*v; }
  #pragma unroll
  for(int o=1;o<16;o<<=1)
    #pragma unroll
    for(int r=0;r<4;r++){ sm[r]+=__shfl_xor(sm[r],o); sq[r]+=__shfl_xor(sq[r],o); }
  float mu[4], rs[4];
  #pragma unroll
  for(int r=0;r<4;r++){
    mu[r] = sm[r]*(1.f/256.f);
    float var = sq[r]*(1.f/256.f) - mu[r]*mu[r];
    rs[r] = rsqrtf(var + 1e-5f);
  }
  #pragma unroll
  for(int j=0;j<16;j++){
    int col = j*16 + (lane&15);
    float w = b2f(mnw[col]), bb = b2f(mnb[col]);
    #pragma unroll
    for(int r=0;r<4;r++){
      size_t m = gm0 + wid*16 + quad*4 + r;
      float xn = X[m*256 + col] + (acc[j][r]-mu[r])*rs[r]*w + bb;
      X[m*256 + col] = xn;
      acc[j][r] = xn;
    }
  }
  if (!LAST){
    float sm2[4]={0,0,0,0}, sq2[4]={0,0,0,0};
    #pragma unroll
    for(int j=0;j<16;j++)
      #pragma unroll
      for(int r=0;r<4;r++){ float v=acc[j][r]; sm2[r]+=v; sq2[r]+=v*v; }
    #pragma unroll
    for(int o=1;o<16;o<<=1)
      #pragma unroll
      for(int r=0;r<4;r++){ sm2[r]+=__shfl_xor(sm2[r],o); sq2[r]+=__shfl_xor(sq2[r],o); }
    float mu2[4], rs2[4];
    #pragma unroll
    for(int r=0;r<4;r++){
      mu2[r] = sm2[r]*(1.f/256.f);
      float var = sq2[r]*(1.f/256.f) - mu2[r]*mu2[r];
      rs2[r] = rsqrtf(var + 1e-5f);
    }
    #pragma unroll
    for(int j=0;j<16;j++){
      int col = j*16 + (lane&15);
      float w = b2f(lnw_n[col]), bb = b2f(lnb_n[col]);
      #pragma unroll
      for(int r=0;r<4;r++){
        size_t m = gm0 + wid*16 + quad*4 + r;
        float vv = (acc[j][r]-mu2[r])*rs2[r]*w + bb;
        u16 hi = f2b(vv);
        xnh[m*256 + col] = hi;
        xnl[m*256 + col] = f2b(vv - b2f(hi));
      }
    }
  }
}

// ---------------- final transpose ----------------
__global__ void k_tr(const float* __restrict__ x, void* __restrict__ out, const int* __restrict__ flag){
  __shared__ float tile[32][129];
  int isbf = *flag;
  int l0 = blockIdx.x*128, c0 = blockIdx.y*32, g = blockIdx.z;
  int tid = threadIdx.x;
  for(int it=0; it<16; ++it){
    int idx = it*256 + tid;
    int lj = idx>>5, ci = idx&31;
    tile[ci][lj] = x[((size_t)g*4096 + l0+lj)*256 + c0+ci];
  }
  __syncthreads();
  for(int it=0; it<16; ++it){
    int idx = it*256 + tid;
    int lj = idx&127, ci = idx>>7;
    size_t o = ((size_t)g*256 + c0+ci)*4096 + l0+lj;
    float v = tile[ci][lj];
    if (isbf) ((u16*)out)[o] = f2b(v);
    else      ((float*)out)[o] = v;
  }
}

extern "C" void kernel_launch(void* const* d_in, const int* in_sizes, int n_in,
                              void* d_out, int out_size, void* d_ws, size_t ws_size,
                              hipStream_t stream){
  (void)in_sizes; (void)n_in; (void)out_size; (void)ws_size;
  const int* rl = (const int*)d_in[15];

  char* ws = (char*)d_ws;
  float* X     = (float*)(ws);                   // 32 MB fp32 residual
  float* XF    = (float*)(ws + 33554432);        // 32 MB fp32 x (g,l,256)
  u16*   ZB    = (u16*)  (ws + 67108864);        // 16 MB bf16 z
  u16*   XNl   = (u16*)  (ws + 83886080);        // 16 MB next-LN1 lo
  u16*   XCF   = (u16*)  (ws + 100663296);       // 16 MB (XCB contiguous after)
  u16*   XCB   = (u16*)  (ws + 117440512);       // 16 MB
  u16*   DF    = (u16*)  (ws + 134217728);       // 16 MB (DB contiguous after)
  u16*   DB    = (u16*)  (ws + 150994944);       // 16 MB
  u16*   BCF   = (u16*)  (ws + 167772160);       // 1 MB  (BCB contiguous after)
  u16*   BCB   = (u16*)  (ws + 168820736);       // 1 MB
  u16*   BCOMB = (u16*)  (ws + 169869312);       // 0.75 MB
  float* AGA   = (float*)(ws + 170655744);       // 16 MB aggregate A  } XNh aliases AGA:
  u16*   XNh   = (u16*)  (ws + 170655744);       //                    } XNh read by gemm0 before scanlb writes AGA
  float* AGB   = (float*)(ws + 187432960);       // 16 MB aggregate B
  float* HINC  = (float*)(ws + 204210176);       // 16 MB inclusive states
  float* YF    = (float*)(ws + 220987392);       // 32 MB pre-gate y_fwd fp32
  float* YB    = (float*)(ws + 254541824);       // 32 MB pre-gate y_bwd fp32
  u16*   WCVT  = (u16*)  (ws + 288096256);       // ~1.73 MB canonical bf16 weights
  u32*   FLAGS = (u32*)  (ws + 289824768);       // 32 KB lookback flags [4][16][128]
  u32*   TICKET= (u32*)  (ws + 289857536);       // 16 B per-layer ticket counters
  int*   FLAG  = (int*)  (ws + 289857600);       // dtype flag

  u16* W_lnw  = WCVT + 0;
  u16* W_lnb  = WCVT + 1024;
  u16* W_inp  = WCVT + 2048;
  u16* W_cw   = WCVT + 526336;
  u16* W_cb   = WCVT + 530432;
  u16* W_xp   = WCVT + 531456;
  u16* W_dtw  = WCVT + 564224;
  u16* W_dtb  = WCVT + 580608;
  u16* W_Al   = WCVT + 581632;
  u16* W_Abl  = WCVT + 589824;
  u16* W_D    = WCVT + 598016;
  u16* W_outp = WCVT + 599040;
  u16* W_mnw  = WCVT + 861184;
  u16* W_mnb  = WCVT + 862208;

  k_detect<<<1,64,0,stream>>>((const u16*)d_in[1], FLAG);
  k_zero<<<1,256,0,stream>>>(FLAGS);   // zeroes FLAGS (8192 u32) + TICKET (4 u32), contiguous

  CvtTable t;
  const int idxs[14] = {1,2,3,4,5,6,7,8,9,10,11,12,13,14};
  u16* dsts[14] = {W_lnw,W_lnb,W_inp,W_cw,W_cb,W_xp,W_dtw,W_dtb,W_Al,W_Abl,W_D,W_outp,W_mnw,W_mnb};
  const int ns[14] = {1024,1024,524288,4096,1024,32768,16384,1024,8192,8192,1024,262144,1024,1024};
  for(int i=0;i<14;i++){ t.src[i]=d_in[idxs[i]]; t.dst[i]=dsts[i]; t.n[i]=ns[i]; }
  k_cvt<<<dim3(32,14),256,0,stream>>>(t, FLAG);

  k_mean<<<dim3(32,8,8),256,0,stream>>>(d_in[0], rl, X, FLAG);
  k_prep<<<dim3(384,4),256,0,stream>>>(W_dtw, W_xp, BCOMB);
  k_ln1<<<8192,256,0,stream>>>(X, XNh, XNl, W_lnw, W_lnb, 0);

  for(int layer=0; layer<4; ++layer){
    k_gemm<0><<<dim3(256,4),256,0,stream>>>(XNh, XNl, W_inp + (size_t)layer*512*256,
                                            nullptr, XF, 256, nullptr, ZB);
    k_conv<<<dim3(128,8),256,0,stream>>>(XF, W_cw, W_cb, XCF, XCB, layer);
    k_gemm<1><<<dim3(512,3),256,0,stream>>>(XCF, nullptr, BCOMB + (size_t)layer*384*256,
                                            DF, nullptr, 256, W_dtb + layer*256, BCF);
    k_scanlb<<<2048,256,0,stream>>>(DF, DB, XCF, XCB, BCF, BCB, XF,
                                    W_Al, W_Abl, W_D, W_cw, W_cb,
                                    AGA, AGB, HINC, FLAGS, TICKET, YF, YB, layer);
    if (layer < 3){
      k_outproj<0><<<dim3(64,8),256,0,stream>>>(YF, YB, ZB, W_outp + (size_t)layer*256*256,
                                                X, XNh, XNl,
                                                W_mnw + layer*256, W_mnb + layer*256,
                                                W_lnw + (layer+1)*256, W_lnb + (layer+1)*256);
    } else {
      k_outproj<1><<<dim3(64,8),256,0,stream>>>(YF, YB, ZB, W_outp + (size_t)layer*256*256,
                                                X, XNh, XNl,
                                                W_mnw + layer*256, W_mnb + layer*256,
                                                W_lnw, W_lnb);
    }
  }
  k_tr<<<dim3(32,8,8),256,0,stream>>>(X, d_out, FLAG);
}

// Round 10
// 1244.284 us; speedup vs baseline: 6.1127x; 6.1127x over previous
//
#include <hip/hip_runtime.h>
#include <hip/hip_bf16.h>
#include <cstdint>
#include <cstddef>

typedef unsigned short u16;
typedef unsigned int   u32;

typedef short s16x8 __attribute__((ext_vector_type(8)));
typedef float f32x4 __attribute__((ext_vector_type(4)));

__device__ __forceinline__ float b2f(u16 u){ u32 x = ((u32)u)<<16; float f; __builtin_memcpy(&f,&x,4); return f; }
__device__ __forceinline__ u16  f2b(float f){ u32 x; __builtin_memcpy(&x,&f,4); u32 r = x + 0x7FFFu + ((x>>16)&1u); return (u16)(r>>16); }

__device__ __forceinline__ void unpack8(uint4 v, float* o){
  o[0]=b2f((u16)v.x); o[1]=b2f((u16)(v.x>>16));
  o[2]=b2f((u16)v.y); o[3]=b2f((u16)(v.y>>16));
  o[4]=b2f((u16)v.z); o[5]=b2f((u16)(v.z>>16));
  o[6]=b2f((u16)v.w); o[7]=b2f((u16)(v.w>>16));
}

__device__ __forceinline__ void gl_lds16(const u16* g, u16* l){
  __builtin_amdgcn_global_load_lds((const __attribute__((address_space(1))) u32*)g,
                                   (__attribute__((address_space(3))) u32*)l, 16, 0, 0);
}

// ---------------- dtype detect ----------------
__global__ void k_detect(const u16* __restrict__ lnw, int* __restrict__ flag){
  if (threadIdx.x==0 && blockIdx.x==0) *flag = (lnw[0] == 0x3F80) ? 1 : 0;
}

// ---------------- convert weights to canonical bf16 ----------------
struct CvtTable { const void* src[14]; u16* dst[14]; int n[14]; };
__global__ void k_cvt(CvtTable t, const int* __restrict__ flag){
  int ti = blockIdx.y;
  int n = t.n[ti];
  int isbf = *flag;
  const u16*  sb = (const u16*)t.src[ti];
  const float* sf = (const float*)t.src[ti];
  u16* d = t.dst[ti];
  for (int i = blockIdx.x*256 + threadIdx.x; i < n; i += gridDim.x*256)
    d[i] = isbf ? sb[i] : f2b(sf[i]);
}

// ---------------- segment mean ----------------
__global__ void k_mean(const void* __restrict__ data, const int* __restrict__ rl,
                       float* __restrict__ x, const int* __restrict__ flag){
  __shared__ float tile[32][129];
  int isbf = *flag;
  const u16*  db = (const u16*)data;
  const float* df_ = (const float*)data;
  int g = blockIdx.z, c0 = blockIdx.y*32, l0 = blockIdx.x*128;
  int tid = threadIdx.x;
  int off=0; for(int i=0;i<g;i++) off += rl[i];
  int cnt = rl[g];
  float inv = 1.0f/(float)cnt;
  for(int it=0; it<16; ++it){
    int idx = it*256 + tid;
    int ci = idx>>7, lj = idx&127;
    float acc = 0.f;
    for(int b=0;b<cnt;b++){
      size_t gi = ((size_t)(off+b)*256 + (c0+ci)) * 4096 + (l0+lj);
      acc += isbf ? b2f(db[gi]) : df_[gi];
    }
    tile[ci][lj] = acc*inv;
  }
  __syncthreads();
  for(int it=0; it<16; ++it){
    int idx = it*256 + tid;
    int lj = idx>>5, ci = idx&31;
    x[ ((size_t)g*4096 + (l0+lj))*256 + (c0+ci) ] = tile[ci][lj];
  }
}

// ---------------- Bcomb prep ----------------
__global__ void k_prep(const u16* __restrict__ dtp, const u16* __restrict__ xpw, u16* __restrict__ bcomb){
  int layer = blockIdx.y, row = blockIdx.x, c = threadIdx.x;
  u16 out;
  if (row < 256){
    float acc = 0.f;
    #pragma unroll
    for(int r=0;r<16;r++)
      acc += b2f(dtp[(size_t)layer*4096 + row*16 + r]) * b2f(xpw[(size_t)layer*8192 + r*256 + c]);
    out = f2b(acc);
  } else if (row < 272){
    out = xpw[(size_t)layer*8192 + (16 + row - 256)*256 + c];
  } else {
    out = 0;
  }
  bcomb[((size_t)layer*384 + row)*256 + c] = out;
}

// ---------------- LN1 (layer 0 only), single bf16 output ----------------
__global__ void k_ln1(const float* __restrict__ x, u16* __restrict__ xn,
                      const u16* __restrict__ w, const u16* __restrict__ b, int layer){
  int wid = threadIdx.x>>6, lane = threadIdx.x&63;
  int row = blockIdx.x*4 + wid;
  const float* xr = x + (size_t)row*256;
  float4 v = *(const float4*)(xr + lane*4);
  float s = v.x+v.y+v.z+v.w;
  float q = v.x*v.x+v.y*v.y+v.z*v.z+v.w*v.w;
  for(int o=32;o;o>>=1){ s += __shfl_xor(s,o); q += __shfl_xor(q,o); }
  float mu = s*(1.f/256.f);
  float var = q*(1.f/256.f) - mu*mu;
  float rs = rsqrtf(var + 1e-5f);
  const u16* wp = w + layer*256 + lane*4;
  const u16* bp = b + layer*256 + lane*4;
  float vv[4] = {v.x,v.y,v.z,v.w};
  u16 h4[4];
  #pragma unroll
  for(int k2=0;k2<4;k2++)
    h4[k2] = f2b( (vv[k2]-mu)*rs*b2f(wp[k2]) + b2f(bp[k2]) );
  uint2 oh; oh.x = (u32)h4[0] | ((u32)h4[1]<<16); oh.y = (u32)h4[2] | ((u32)h4[3]<<16);
  *(uint2*)(xn + (size_t)row*256 + lane*4) = oh;
}

// ---------------- bf16 NT GEMM, 128x128 tile, BK=64, K=256, XOR-swizzled LDS ----------------
// MODE 0: in_proj: n<256 -> x fp32 (C0f, ld 256), n>=256 -> z bf16 (C1)
// MODE 1: x_proj/delta: softplus+bias -> C0 bf16, raw B/C rows -> C1 bf16
template<int MODE>
__global__ __launch_bounds__(256)
void k_gemm(const u16* __restrict__ A,
            const u16* __restrict__ B,
            u16* __restrict__ C0, float* __restrict__ C0f, int ldC,
            const u16* __restrict__ bias, u16* __restrict__ C1){
  __shared__ u16 As[128*64];
  __shared__ u16 Bs[128*64];
  int tid = threadIdx.x, wid = tid>>6, lane = tid&63;
  int m0 = blockIdx.x*128, n0 = blockIdx.y*128;
  f32x4 acc[4][4];
  #pragma unroll
  for(int i=0;i<4;i++)
    #pragma unroll
    for(int j=0;j<4;j++) acc[i][j] = (f32x4){0.f,0.f,0.f,0.f};
  int lrow  = lane>>3;
  int scol  = ((lane&7) ^ lrow) * 8;
  int rm = (wid&1)*64, cn = (wid>>1)*64;
  for(int k0=0;k0<256;k0+=64){
    #pragma unroll
    for(int it=0; it<4; ++it){
      int chunk = wid*4 + it;
      int row = chunk*8 + lrow;
      gl_lds16(A + (size_t)(m0+row)*256 + k0 + scol, As + chunk*512 + lane*8);
      gl_lds16(B + (size_t)(n0+row)*256 + k0 + scol, Bs + chunk*512 + lane*8);
    }
    __syncthreads();
    #pragma unroll
    for(int kk=0;kk<2;kk++){
      s16x8 af[4], bfr[4];
      #pragma unroll
      for(int i=0;i<4;i++){
        int ar = rm + i*16 + (lane&15);
        int ap = (kk*4 + (lane>>4)) ^ (ar&7);
        af[i]  = *(const s16x8*)(As + ar*64 + ap*8);
        int br = cn + i*16 + (lane&15);
        int bp = (kk*4 + (lane>>4)) ^ (br&7);
        bfr[i] = *(const s16x8*)(Bs + br*64 + bp*8);
      }
      #pragma unroll
      for(int i=0;i<4;i++)
        #pragma unroll
        for(int j=0;j<4;j++)
          acc[i][j] = __builtin_amdgcn_mfma_f32_16x16x32_bf16(af[i], bfr[j], acc[i][j], 0,0,0);
    }
    __syncthreads();
  }
  #pragma unroll
  for(int i=0;i<4;i++){
    #pragma unroll
    for(int j=0;j<4;j++){
      int n  = n0 + cn + j*16 + (lane&15);
      int mB = m0 + rm + i*16 + ((lane>>4)<<2);
      #pragma unroll
      for(int r=0;r<4;r++){
        float val = acc[i][j][r];
        int m = mB + r;
        if (MODE==0){
          if (n < 256) C0f[(size_t)m*256 + n] = val;
          else         C1[(size_t)m*256 + (n-256)] = f2b(val);
        } else {
          if (n < 256){
            float v2 = val + b2f(bias[n]);
            float sp = (v2 > 15.f) ? v2 : __logf(1.f + __expf(v2));
            C0[(size_t)m*256 + n] = f2b(sp);
          } else if (n < 272){
            C1[(size_t)m*16 + (n-256)] = f2b(val);
          }
        }
      }
    }
  }
}

// ---------------- depthwise conv + SiLU from fp32 x (g,l,256), 32 positions per block ----------------
__global__ void k_conv(const float* __restrict__ xf, const u16* __restrict__ cw,
                       const u16* __restrict__ cb, u16* __restrict__ xcf, u16* __restrict__ xcb_, int layer){
  int l0 = blockIdx.x*32, g = blockIdx.y, d = threadIdx.x;
  float w[4];
  #pragma unroll
  for(int j=0;j<4;j++) w[j] = b2f(cw[(size_t)layer*1024 + d*4 + j]);
  float bb = b2f(cb[layer*256 + d]);
  float xv[38];
  #pragma unroll
  for(int t=0;t<38;t++){
    int lp = l0 - 3 + t;
    xv[t] = (lp>=0 && lp<4096) ? xf[((size_t)g*4096 + lp)*256 + d] : 0.f;
  }
  #pragma unroll
  for(int i=0;i<32;i++){
    float af = bb, ab = bb;
    #pragma unroll
    for(int j=0;j<4;j++){ af += w[j]*xv[i+j]; ab += w[j]*xv[i+6-j]; }
    af = af / (1.f + __expf(-af));
    ab = ab / (1.f + __expf(-ab));
    size_t o = ((size_t)g*4096 + (l0+i))*256 + d;
    xcf[o]  = f2b(af);
    xcb_[o] = f2b(ab);
  }
}

// ---------------- scan pass 1, chunk=32 ----------------
__global__ __launch_bounds__(256)
void k_scan1(const u16* __restrict__ df, const u16* __restrict__ db,
             const u16* __restrict__ uf, const u16* __restrict__ ub,
             const u16* __restrict__ bcf, const u16* __restrict__ bcb,
             const u16* __restrict__ Alog, const u16* __restrict__ Ablog,
             float* __restrict__ abuf, float* __restrict__ bbuf, int layer){
  int c = blockIdx.x, g = blockIdx.y, dir = blockIdx.z, d = threadIdx.x;
  const u16* dl = dir ? db : df;
  const u16* uu = dir ? ub : uf;
  const u16* bc = dir ? bcb : bcf;
  const u16* Al = dir ? Ablog : Alog;
  float An[8], h[8], ap[8];
  #pragma unroll
  for(int n=0;n<8;n++){
    An[n] = -__expf(b2f(Al[(size_t)layer*2048 + d*8 + n]));
    h[n] = 0.f; ap[n] = 1.f;
  }
  #pragma unroll 4
  for(int t=0;t<32;t++){
    int ts = c*32 + t;
    int tg = dir ? (4095 - ts) : ts;
    size_t rowo = (size_t)g*4096 + tg;
    float dv = b2f(dl[rowo*256 + d]);
    float uv = b2f(uu[rowo*256 + d]);
    uint4 bv = *(const uint4*)(bc + rowo*16);
    float bn[8]; unpack8(bv, bn);
    float du = dv*uv;
    #pragma unroll
    for(int n=0;n<8;n++){
      float da = __expf(dv*An[n]);
      h[n] = fmaf(da, h[n], du*bn[n]);
      ap[n] *= da;
    }
  }
  size_t base = ((((size_t)dir*8+g)*128 + c)*256 + d)*8;
  *(float4*)(abuf+base)   = (float4){ap[0],ap[1],ap[2],ap[3]};
  *(float4*)(abuf+base+4) = (float4){ap[4],ap[5],ap[6],ap[7]};
  *(float4*)(bbuf+base)   = (float4){h[0],h[1],h[2],h[3]};
  *(float4*)(bbuf+base+4) = (float4){h[4],h[5],h[6],h[7]};
}

// ---------------- scan pass 2, 128 chunks, 512 blocks x 64 threads ----------------
__global__ void k_scan2(const float* __restrict__ abuf, const float* __restrict__ bbuf,
                        float* __restrict__ hs){
  int dblk = blockIdx.x, g = blockIdx.y, dir = blockIdx.z;
  int n = threadIdx.x & 7, dd = threadIdx.x >> 3;   // 64 threads: 8 d x 8 n
  int d = dblk*8 + dd;
  float h = 0.f;
  size_t gofs = (((size_t)dir*8+g)*128);
  #pragma unroll 4
  for(int c=0;c<128;c++){
    size_t idx = ((gofs + c)*256 + d)*8 + n;
    hs[idx] = h;
    h = fmaf(abuf[idx], h, bbuf[idx]);
  }
}

// ---------------- fused bidirectional replay, chunk=32: y_bwd in LDS, single bf16 y out ----------------
__global__ __launch_bounds__(256)
void k_scanY(const u16* __restrict__ df, const u16* __restrict__ db,
             const float* __restrict__ xf, const u16* __restrict__ zb,
             const u16* __restrict__ bcf, const u16* __restrict__ bcb,
             const u16* __restrict__ Alog, const u16* __restrict__ Ablog,
             const u16* __restrict__ Dp, const u16* __restrict__ cw, const u16* __restrict__ cb,
             const float* __restrict__ hs,
             u16* __restrict__ yhi, int layer){
  __shared__ float ybs[32*256];   // 32 KB pre-gate y_bwd; ybs[t*256+tid], same-thread write/read (no barrier)
  int c = blockIdx.x, g = blockIdx.y, d = threadIdx.x;
  int l0 = c*32;
  float Dd = b2f(Dp[layer*256 + d]);
  float w0 = b2f(cw[(size_t)layer*1024 + d*4 + 0]);
  float w1 = b2f(cw[(size_t)layer*1024 + d*4 + 1]);
  float w2 = b2f(cw[(size_t)layer*1024 + d*4 + 2]);
  float w3 = b2f(cw[(size_t)layer*1024 + d*4 + 3]);
  float cbb = b2f(cb[layer*256 + d]);
  const float* xrow = xf + (size_t)g*4096*256 + d;          // x[l] at xrow[l*256]
  const u16*  zrow = zb + (size_t)g*4096*256 + d;           // z[l] at zrow[l*256]
  float An[8], h[8];
  // ---- bwd half (global bwd chunk 127-c covers same positions), rows descending ----
  {
    #pragma unroll
    for(int n=0;n<8;n++) An[n] = -__expf(b2f(Ablog[(size_t)layer*2048 + d*8 + n]));
    size_t base = ((((size_t)8+g)*128 + (127-c))*256 + d)*8;
    float4 h0 = *(const float4*)(hs+base);
    float4 h1 = *(const float4*)(hs+base+4);
    h[0]=h0.x; h[1]=h0.y; h[2]=h0.z; h[3]=h0.w;
    h[4]=h1.x; h[5]=h1.y; h[6]=h1.z; h[7]=h1.w;
    // reversed-direction causal conv at pos p uses x[p..p+3]
    float xw1 = (l0+32<4096) ? xrow[(size_t)(l0+32)*256] : 0.f;
    float xw2 = (l0+33<4096) ? xrow[(size_t)(l0+33)*256] : 0.f;
    float xw3 = (l0+34<4096) ? xrow[(size_t)(l0+34)*256] : 0.f;
    #pragma unroll 4
    for(int q=0;q<32;q++){
      int t = 31 - q;
      size_t rowo = (size_t)g*4096 + l0 + t;
      float x0 = xrow[(size_t)(l0+t)*256];
      float ucv = cbb + w3*x0 + w2*xw1 + w1*xw2 + w0*xw3;
      xw3 = xw2; xw2 = xw1; xw1 = x0;
      float uv = ucv / (1.f + __expf(-ucv));
      float dv = b2f(db[rowo*256 + d]);
      uint4 bv = *(const uint4*)(bcb + rowo*16);
      uint4 cv = *(const uint4*)(bcb + rowo*16 + 8);
      float bn[8], cn_[8];
      unpack8(bv, bn); unpack8(cv, cn_);
      float du = dv*uv;
      float y = 0.f;
      #pragma unroll
      for(int n=0;n<8;n++){
        float da = __expf(dv*An[n]);
        h[n] = fmaf(da, h[n], du*bn[n]);
        y = fmaf(h[n], cn_[n], y);
      }
      ybs[t*256 + d] = y + Dd*uv;     // pre-gate y_bwd
    }
  }
  // ---- fwd half, rows ascending; add y_bwd, gate once, store single bf16 ----
  {
    #pragma unroll
    for(int n=0;n<8;n++) An[n] = -__expf(b2f(Alog[(size_t)layer*2048 + d*8 + n]));
    size_t base = (((size_t)g*128 + c)*256 + d)*8;
    float4 h0 = *(const float4*)(hs+base);
    float4 h1 = *(const float4*)(hs+base+4);
    h[0]=h0.x; h[1]=h0.y; h[2]=h0.z; h[3]=h0.w;
    h[4]=h1.x; h[5]=h1.y; h[6]=h1.z; h[7]=h1.w;
    // forward causal conv at pos p uses x[p-3..p]
    float wm1 = (l0-1>=0) ? xrow[(size_t)(l0-1)*256] : 0.f;
    float wm2 = (l0-2>=0) ? xrow[(size_t)(l0-2)*256] : 0.f;
    float wm3 = (l0-3>=0) ? xrow[(size_t)(l0-3)*256] : 0.f;
    #pragma unroll 4
    for(int t=0;t<32;t++){
      size_t rowo = (size_t)g*4096 + l0 + t;
      float x0 = xrow[(size_t)(l0+t)*256];
      float ucv = cbb + w0*wm3 + w1*wm2 + w2*wm1 + w3*x0;
      wm3 = wm2; wm2 = wm1; wm1 = x0;
      float uv = ucv / (1.f + __expf(-ucv));
      float dv = b2f(df[rowo*256 + d]);
      uint4 bv = *(const uint4*)(bcf + rowo*16);
      uint4 cv = *(const uint4*)(bcf + rowo*16 + 8);
      float bn[8], cn_[8];
      unpack8(bv, bn); unpack8(cv, cn_);
      float du = dv*uv;
      float y = 0.f;
      #pragma unroll
      for(int n=0;n<8;n++){
        float da = __expf(dv*An[n]);
        h[n] = fmaf(da, h[n], du*bn[n]);
        y = fmaf(h[n], cn_[n], y);
      }
      y += Dd*uv;
      y += ybs[t*256 + d];
      float zv = b2f(zrow[(size_t)(l0+t)*256]);
      float yv = y * 0.5f * zv / (1.f + __expf(-zv));
      yhi[rowo*256 + d] = f2b(yv);
    }
  }
}

// ---------------- out_proj GEMM (single bf16 A) + LN2 + residual (+ next LN1 single bf16) ----------------
template<int LAST>
__global__ __launch_bounds__(256)
void k_outproj(const u16* __restrict__ yhi,
               const u16* __restrict__ Bw,
               float* __restrict__ X, u16* __restrict__ xnh,
               const u16* __restrict__ mnw, const u16* __restrict__ mnb,
               const u16* __restrict__ lnw_n, const u16* __restrict__ lnb_n){
  __shared__ u16 Ash[64*64];   // 8 KB
  __shared__ u16 Bs[256*64];   // 32 KB
  int tid = threadIdx.x, wid = tid>>6, lane = tid&63;
  int c = blockIdx.x, g = blockIdx.y;
  size_t row0 = (size_t)g*4096 + c*64;
  f32x4 acc[16];
  #pragma unroll
  for(int j=0;j<16;j++) acc[j] = (f32x4){0.f,0.f,0.f,0.f};
  int lrow = lane>>3;
  int scol = ((lane&7) ^ lrow) * 8;
  for(int k0=0;k0<256;k0+=64){
    #pragma unroll
    for(int it=0; it<2; ++it){
      int chunk = wid*2 + it;
      int row = chunk*8 + lrow;
      gl_lds16(yhi + (row0+row)*256 + k0 + scol, Ash + chunk*512 + lane*8);
    }
    #pragma unroll
    for(int it=0; it<8; ++it){
      int chunk = wid*8 + it;
      int row = chunk*8 + lrow;
      gl_lds16(Bw + (size_t)row*256 + k0 + scol, Bs + chunk*512 + lane*8);
    }
    __syncthreads();
    #pragma unroll
    for(int kk=0;kk<2;kk++){
      int ar = wid*16 + (lane&15);
      int q  = kk*4 + (lane>>4);
      s16x8 afh = *(const s16x8*)(Ash + ar*64 + (q^(ar&7))*8);
      #pragma unroll
      for(int j=0;j<16;j++){
        int br = j*16 + (lane&15);
        s16x8 bfv = *(const s16x8*)(Bs + br*64 + (q^(br&7))*8);
        acc[j] = __builtin_amdgcn_mfma_f32_16x16x32_bf16(afh, bfv, acc[j], 0,0,0);
      }
    }
    __syncthreads();
  }
  // ---- epilogue: LN2 + residual (+ next-layer LN1) ----
  size_t gm0 = row0;
  int quad = lane>>4;
  float sm[4]={0,0,0,0}, sq[4]={0,0,0,0};
  #pragma unroll
  for(int j=0;j<16;j++)
    #pragma unroll
    for(int r=0;r<4;r++){ float v=acc[j][r]; sm[r]+=v; sq[r]+=v*v; }
  #pragma unroll
  for(int o=1;o<16;o<<=1)
    #pragma unroll
    for(int r=0;r<4;r++){ sm[r]+=__shfl_xor(sm[r],o); sq[r]+=__shfl_xor(sq[r],o); }
  float mu[4], rs[4];
  #pragma unroll
  for(int r=0;r<4;r++){
    mu[r] = sm[r]*(1.f/256.f);
    float var = sq[r]*(1.f/256.f) - mu[r]*mu[r];
    rs[r] = rsqrtf(var + 1e-5f);
  }
  #pragma unroll
  for(int j=0;j<16;j++){
    int col = j*16 + (lane&15);
    float w = b2f(mnw[col]), bb = b2f(mnb[col]);
    #pragma unroll
    for(int r=0;r<4;r++){
      size_t m = gm0 + wid*16 + quad*4 + r;
      float xn = X[m*256 + col] + (acc[j][r]-mu[r])*rs[r]*w + bb;
      X[m*256 + col] = xn;
      acc[j][r] = xn;
    }
  }
  if (!LAST){
    float sm2[4]={0,0,0,0}, sq2[4]={0,0,0,0};
    #pragma unroll
    for(int j=0;j<16;j++)
      #pragma unroll
      for(int r=0;r<4;r++){ float v=acc[j][r]; sm2[r]+=v; sq2[r]+=v*v; }
    #pragma unroll
    for(int o=1;o<16;o<<=1)
      #pragma unroll
      for(int r=0;r<4;r++){ sm2[r]+=__shfl_xor(sm2[r],o); sq2[r]+=__shfl_xor(sq2[r],o); }
    float mu2[4], rs2[4];
    #pragma unroll
    for(int r=0;r<4;r++){
      mu2[r] = sm2[r]*(1.f/256.f);
      float var = sq2[r]*(1.f/256.f) - mu2[r]*mu2[r];
      rs2[r] = rsqrtf(var + 1e-5f);
    }
    #pragma unroll
    for(int j=0;j<16;j++){
      int col = j*16 + (lane&15);
      float w = b2f(lnw_n[col]), bb = b2f(lnb_n[col]);
      #pragma unroll
      for(int r=0;r<4;r++){
        size_t m = gm0 + wid*16 + quad*4 + r;
        float vv = (acc[j][r]-mu2[r])*rs2[r]*w + bb;
        xnh[m*256 + col] = f2b(vv);
      }
    }
  }
}

// ---------------- final transpose ----------------
__global__ void k_tr(const float* __restrict__ x, void* __restrict__ out, const int* __restrict__ flag){
  __shared__ float tile[32][129];
  int isbf = *flag;
  int l0 = blockIdx.x*128, c0 = blockIdx.y*32, g = blockIdx.z;
  int tid = threadIdx.x;
  for(int it=0; it<16; ++it){
    int idx = it*256 + tid;
    int lj = idx>>5, ci = idx&31;
    tile[ci][lj] = x[((size_t)g*4096 + l0+lj)*256 + c0+ci];
  }
  __syncthreads();
  for(int it=0; it<16; ++it){
    int idx = it*256 + tid;
    int lj = idx&127, ci = idx>>7;
    size_t o = ((size_t)g*256 + c0+ci)*4096 + l0+lj;
    float v = tile[ci][lj];
    if (isbf) ((u16*)out)[o] = f2b(v);
    else      ((float*)out)[o] = v;
  }
}

extern "C" void kernel_launch(void* const* d_in, const int* in_sizes, int n_in,
                              void* d_out, int out_size, void* d_ws, size_t ws_size,
                              hipStream_t stream){
  (void)in_sizes; (void)n_in; (void)out_size; (void)ws_size;
  const int* rl = (const int*)d_in[15];

  char* ws = (char*)d_ws;
  float* X    = (float*)(ws);                    // 32 MB fp32 residual
  float* XF   = (float*)(ws + 33554432);         // 32 MB fp32 x (g,l,256)
  u16*  ZB    = (u16*) (ws + 67108864);          // 16 MB bf16 z (g,l,256)
  u16*  XCF   = (u16*) (ws + 100663296);         // 16 MB (XCB contiguous after); YHI aliases (XCF dead after scan1)
  u16*  XCB   = (u16*) (ws + 117440512);         // 16 MB
  u16*  DF    = (u16*) (ws + 134217728);         // 16 MB (DB contiguous after)
  u16*  DB    = (u16*) (ws + 150994944);         // 16 MB
  u16*  BCF   = (u16*) (ws + 167772160);         // 1 MB  (BCB contiguous after)
  u16*  BCB   = (u16*) (ws + 168820736);         // 1 MB
  u16*  BCOMB = (u16*) (ws + 169869312);         // 0.75 MB
  float* ABUF = (float*)(ws + 170655744);        // 16 MB } XNh aliases ABUF (lifetime-disjoint:
  u16*  XNh   = (u16*) (ws + 170655744);         //       } XNh read by gemm0 before scan1 writes ABUF)
  float* BBUF = (float*)(ws + 187432960);        // 16 MB
  float* HS   = (float*)(ws + 204210176);        // 16 MB
  u16*  WCVT  = (u16*) (ws + 220987392);         // ~1.73 MB canonical bf16 weights
  int*  FLAG  = (int*) (ws + 222715904);

  u16* YHI = XCF;

  u16* W_lnw  = WCVT + 0;
  u16* W_lnb  = WCVT + 1024;
  u16* W_inp  = WCVT + 2048;
  u16* W_cw   = WCVT + 526336;
  u16* W_cb   = WCVT + 530432;
  u16* W_xp   = WCVT + 531456;
  u16* W_dtw  = WCVT + 564224;
  u16* W_dtb  = WCVT + 580608;
  u16* W_Al   = WCVT + 581632;
  u16* W_Abl  = WCVT + 589824;
  u16* W_D    = WCVT + 598016;
  u16* W_outp = WCVT + 599040;
  u16* W_mnw  = WCVT + 861184;
  u16* W_mnb  = WCVT + 862208;

  k_detect<<<1,64,0,stream>>>((const u16*)d_in[1], FLAG);

  CvtTable t;
  const int idxs[14] = {1,2,3,4,5,6,7,8,9,10,11,12,13,14};
  u16* dsts[14] = {W_lnw,W_lnb,W_inp,W_cw,W_cb,W_xp,W_dtw,W_dtb,W_Al,W_Abl,W_D,W_outp,W_mnw,W_mnb};
  const int ns[14] = {1024,1024,524288,4096,1024,32768,16384,1024,8192,8192,1024,262144,1024,1024};
  for(int i=0;i<14;i++){ t.src[i]=d_in[idxs[i]]; t.dst[i]=dsts[i]; t.n[i]=ns[i]; }
  k_cvt<<<dim3(32,14),256,0,stream>>>(t, FLAG);

  k_mean<<<dim3(32,8,8),256,0,stream>>>(d_in[0], rl, X, FLAG);
  k_prep<<<dim3(384,4),256,0,stream>>>(W_dtw, W_xp, BCOMB);
  k_ln1<<<8192,256,0,stream>>>(X, XNh, W_lnw, W_lnb, 0);

  for(int layer=0; layer<4; ++layer){
    k_gemm<0><<<dim3(256,4),256,0,stream>>>(XNh, W_inp + (size_t)layer*512*256,
                                            nullptr, XF, 256, nullptr, ZB);
    k_conv<<<dim3(128,8),256,0,stream>>>(XF, W_cw, W_cb, XCF, XCB, layer);
    k_gemm<1><<<dim3(512,3),256,0,stream>>>(XCF, BCOMB + (size_t)layer*384*256,
                                            DF, nullptr, 256, W_dtb + layer*256, BCF);
    k_scan1<<<dim3(128,8,2),256,0,stream>>>(DF,DB,XCF,XCB,BCF,BCB,W_Al,W_Abl,ABUF,BBUF,layer);
    k_scan2<<<dim3(32,8,2),64,0,stream>>>(ABUF,BBUF,HS);
    k_scanY<<<dim3(128,8),256,0,stream>>>(DF,DB,XF,ZB,BCF,BCB,W_Al,W_Abl,W_D,W_cw,W_cb,HS,YHI,layer);
    if (layer < 3){
      k_outproj<0><<<dim3(64,8),256,0,stream>>>(YHI, W_outp + (size_t)layer*256*256,
                                                X, XNh,
                                                W_mnw + layer*256, W_mnb + layer*256,
                                                W_lnw + (layer+1)*256, W_lnb + (layer+1)*256);
    } else {
      k_outproj<1><<<dim3(64,8),256,0,stream>>>(YHI, W_outp + (size_t)layer*256*256,
                                                X, XNh,
                                                W_mnw + layer*256, W_mnb + layer*256,
                                                W_lnw, W_lnb);
    }
  }
  k_tr<<<dim3(32,8,8),256,0,stream>>>(X, d_out, FLAG);
}

// Round 12
// 1174.426 us; speedup vs baseline: 6.4763x; 1.0595x over previous
//
#include <hip/hip_runtime.h>
#include <hip/hip_bf16.h>
#include <cstdint>
#include <cstddef>

typedef unsigned short u16;
typedef unsigned int   u32;

typedef short s16x8 __attribute__((ext_vector_type(8)));
typedef float f32x4 __attribute__((ext_vector_type(4)));

__device__ __forceinline__ float b2f(u16 u){ u32 x = ((u32)u)<<16; float f; __builtin_memcpy(&f,&x,4); return f; }
__device__ __forceinline__ u16  f2b(float f){ u32 x; __builtin_memcpy(&x,&f,4); u32 r = x + 0x7FFFu + ((x>>16)&1u); return (u16)(r>>16); }

__device__ __forceinline__ void unpack8(uint4 v, float* o){
  o[0]=b2f((u16)v.x); o[1]=b2f((u16)(v.x>>16));
  o[2]=b2f((u16)v.y); o[3]=b2f((u16)(v.y>>16));
  o[4]=b2f((u16)v.z); o[5]=b2f((u16)(v.z>>16));
  o[6]=b2f((u16)v.w); o[7]=b2f((u16)(v.w>>16));
}

__device__ __forceinline__ void gl_lds16(const u16* g, u16* l){
  __builtin_amdgcn_global_load_lds((const __attribute__((address_space(1))) u32*)g,
                                   (__attribute__((address_space(3))) u32*)l, 16, 0, 0);
}

// ---------------- dtype detect ----------------
__global__ void k_detect(const u16* __restrict__ lnw, int* __restrict__ flag){
  if (threadIdx.x==0 && blockIdx.x==0) *flag = (lnw[0] == 0x3F80) ? 1 : 0;
}

// ---------------- convert weights to canonical bf16 ----------------
struct CvtTable { const void* src[14]; u16* dst[14]; int n[14]; };
__global__ void k_cvt(CvtTable t, const int* __restrict__ flag){
  int ti = blockIdx.y;
  int n = t.n[ti];
  int isbf = *flag;
  const u16*  sb = (const u16*)t.src[ti];
  const float* sf = (const float*)t.src[ti];
  u16* d = t.dst[ti];
  for (int i = blockIdx.x*256 + threadIdx.x; i < n; i += gridDim.x*256)
    d[i] = isbf ? sb[i] : f2b(sf[i]);
}

// ---------------- segment mean ----------------
__global__ void k_mean(const void* __restrict__ data, const int* __restrict__ rl,
                       float* __restrict__ x, const int* __restrict__ flag){
  __shared__ float tile[32][129];
  int isbf = *flag;
  const u16*  db = (const u16*)data;
  const float* df_ = (const float*)data;
  int g = blockIdx.z, c0 = blockIdx.y*32, l0 = blockIdx.x*128;
  int tid = threadIdx.x;
  int off=0; for(int i=0;i<g;i++) off += rl[i];
  int cnt = rl[g];
  float inv = 1.0f/(float)cnt;
  for(int it=0; it<16; ++it){
    int idx = it*256 + tid;
    int ci = idx>>7, lj = idx&127;
    float acc = 0.f;
    for(int b=0;b<cnt;b++){
      size_t gi = ((size_t)(off+b)*256 + (c0+ci)) * 4096 + (l0+lj);
      acc += isbf ? b2f(db[gi]) : df_[gi];
    }
    tile[ci][lj] = acc*inv;
  }
  __syncthreads();
  for(int it=0; it<16; ++it){
    int idx = it*256 + tid;
    int lj = idx>>5, ci = idx&31;
    x[ ((size_t)g*4096 + (l0+lj))*256 + (c0+ci) ] = tile[ci][lj];
  }
}

// ---------------- Bcomb prep ----------------
__global__ void k_prep(const u16* __restrict__ dtp, const u16* __restrict__ xpw, u16* __restrict__ bcomb){
  int layer = blockIdx.y, row = blockIdx.x, c = threadIdx.x;
  u16 out;
  if (row < 256){
    float acc = 0.f;
    #pragma unroll
    for(int r=0;r<16;r++)
      acc += b2f(dtp[(size_t)layer*4096 + row*16 + r]) * b2f(xpw[(size_t)layer*8192 + r*256 + c]);
    out = f2b(acc);
  } else if (row < 272){
    out = xpw[(size_t)layer*8192 + (16 + row - 256)*256 + c];
  } else {
    out = 0;
  }
  bcomb[((size_t)layer*384 + row)*256 + c] = out;
}

// ---------------- LN1 (layer 0 only), single bf16 output ----------------
__global__ void k_ln1(const float* __restrict__ x, u16* __restrict__ xn,
                      const u16* __restrict__ w, const u16* __restrict__ b, int layer){
  int wid = threadIdx.x>>6, lane = threadIdx.x&63;
  int row = blockIdx.x*4 + wid;
  const float* xr = x + (size_t)row*256;
  float4 v = *(const float4*)(xr + lane*4);
  float s = v.x+v.y+v.z+v.w;
  float q = v.x*v.x+v.y*v.y+v.z*v.z+v.w*v.w;
  for(int o=32;o;o>>=1){ s += __shfl_xor(s,o); q += __shfl_xor(q,o); }
  float mu = s*(1.f/256.f);
  float var = q*(1.f/256.f) - mu*mu;
  float rs = rsqrtf(var + 1e-5f);
  const u16* wp = w + layer*256 + lane*4;
  const u16* bp = b + layer*256 + lane*4;
  float vv[4] = {v.x,v.y,v.z,v.w};
  u16 h4[4];
  #pragma unroll
  for(int k2=0;k2<4;k2++)
    h4[k2] = f2b( (vv[k2]-mu)*rs*b2f(wp[k2]) + b2f(bp[k2]) );
  uint2 oh; oh.x = (u32)h4[0] | ((u32)h4[1]<<16); oh.y = (u32)h4[2] | ((u32)h4[3]<<16);
  *(uint2*)(xn + (size_t)row*256 + lane*4) = oh;
}

// ---------------- bf16 NT GEMM, 128x128 tile, BK=64, K=256, XOR-swizzled LDS ----------------
// MODE 0: in_proj: n<256 -> x fp32 (C0f, ld 256), n>=256 -> z bf16 (C1)
// MODE 1: x_proj/delta: softplus+bias -> C0 bf16, raw B/C rows -> C1 bf16
template<int MODE>
__global__ __launch_bounds__(256)
void k_gemm(const u16* __restrict__ A,
            const u16* __restrict__ B,
            u16* __restrict__ C0, float* __restrict__ C0f, int ldC,
            const u16* __restrict__ bias, u16* __restrict__ C1){
  __shared__ u16 As[128*64];
  __shared__ u16 Bs[128*64];
  int tid = threadIdx.x, wid = tid>>6, lane = tid&63;
  int m0 = blockIdx.x*128, n0 = blockIdx.y*128;
  f32x4 acc[4][4];
  #pragma unroll
  for(int i=0;i<4;i++)
    #pragma unroll
    for(int j=0;j<4;j++) acc[i][j] = (f32x4){0.f,0.f,0.f,0.f};
  int lrow  = lane>>3;
  int scol  = ((lane&7) ^ lrow) * 8;
  int rm = (wid&1)*64, cn = (wid>>1)*64;
  for(int k0=0;k0<256;k0+=64){
    #pragma unroll
    for(int it=0; it<4; ++it){
      int chunk = wid*4 + it;
      int row = chunk*8 + lrow;
      gl_lds16(A + (size_t)(m0+row)*256 + k0 + scol, As + chunk*512 + lane*8);
      gl_lds16(B + (size_t)(n0+row)*256 + k0 + scol, Bs + chunk*512 + lane*8);
    }
    __syncthreads();
    #pragma unroll
    for(int kk=0;kk<2;kk++){
      s16x8 af[4], bfr[4];
      #pragma unroll
      for(int i=0;i<4;i++){
        int ar = rm + i*16 + (lane&15);
        int ap = (kk*4 + (lane>>4)) ^ (ar&7);
        af[i]  = *(const s16x8*)(As + ar*64 + ap*8);
        int br = cn + i*16 + (lane&15);
        int bp = (kk*4 + (lane>>4)) ^ (br&7);
        bfr[i] = *(const s16x8*)(Bs + br*64 + bp*8);
      }
      #pragma unroll
      for(int i=0;i<4;i++)
        #pragma unroll
        for(int j=0;j<4;j++)
          acc[i][j] = __builtin_amdgcn_mfma_f32_16x16x32_bf16(af[i], bfr[j], acc[i][j], 0,0,0);
    }
    __syncthreads();
  }
  #pragma unroll
  for(int i=0;i<4;i++){
    #pragma unroll
    for(int j=0;j<4;j++){
      int n  = n0 + cn + j*16 + (lane&15);
      int mB = m0 + rm + i*16 + ((lane>>4)<<2);
      #pragma unroll
      for(int r=0;r<4;r++){
        float val = acc[i][j][r];
        int m = mB + r;
        if (MODE==0){
          if (n < 256) C0f[(size_t)m*256 + n] = val;
          else         C1[(size_t)m*256 + (n-256)] = f2b(val);
        } else {
          if (n < 256){
            float v2 = val + b2f(bias[n]);
            float sp = (v2 > 15.f) ? v2 : __logf(1.f + __expf(v2));
            C0[(size_t)m*256 + n] = f2b(sp);
          } else if (n < 272){
            C1[(size_t)m*16 + (n-256)] = f2b(val);
          }
        }
      }
    }
  }
}

// ---------------- depthwise conv + SiLU from fp32 x (g,l,256), 32 positions per block ----------------
__global__ void k_conv(const float* __restrict__ xf, const u16* __restrict__ cw,
                       const u16* __restrict__ cb, u16* __restrict__ xcf, u16* __restrict__ xcb_, int layer){
  int l0 = blockIdx.x*32, g = blockIdx.y, d = threadIdx.x;
  float w[4];
  #pragma unroll
  for(int j=0;j<4;j++) w[j] = b2f(cw[(size_t)layer*1024 + d*4 + j]);
  float bb = b2f(cb[layer*256 + d]);
  float xv[38];
  #pragma unroll
  for(int t=0;t<38;t++){
    int lp = l0 - 3 + t;
    xv[t] = (lp>=0 && lp<4096) ? xf[((size_t)g*4096 + lp)*256 + d] : 0.f;
  }
  #pragma unroll
  for(int i=0;i<32;i++){
    float af = bb, ab = bb;
    #pragma unroll
    for(int j=0;j<4;j++){ af += w[j]*xv[i+j]; ab += w[j]*xv[i+6-j]; }
    af = af / (1.f + __expf(-af));
    ab = ab / (1.f + __expf(-ab));
    size_t o = ((size_t)g*4096 + (l0+i))*256 + d;
    xcf[o]  = f2b(af);
    xcb_[o] = f2b(ab);
  }
}

// ---------------- scan pass 1, chunk=32 ----------------
__global__ __launch_bounds__(256)
void k_scan1(const u16* __restrict__ df, const u16* __restrict__ db,
             const u16* __restrict__ uf, const u16* __restrict__ ub,
             const u16* __restrict__ bcf, const u16* __restrict__ bcb,
             const u16* __restrict__ Alog, const u16* __restrict__ Ablog,
             float* __restrict__ abuf, float* __restrict__ bbuf, int layer){
  int c = blockIdx.x, g = blockIdx.y, dir = blockIdx.z, d = threadIdx.x;
  const u16* dl = dir ? db : df;
  const u16* uu = dir ? ub : uf;
  const u16* bc = dir ? bcb : bcf;
  const u16* Al = dir ? Ablog : Alog;
  float An[8], h[8], ap[8];
  #pragma unroll
  for(int n=0;n<8;n++){
    An[n] = -__expf(b2f(Al[(size_t)layer*2048 + d*8 + n]));
    h[n] = 0.f; ap[n] = 1.f;
  }
  #pragma unroll 4
  for(int t=0;t<32;t++){
    int ts = c*32 + t;
    int tg = dir ? (4095 - ts) : ts;
    size_t rowo = (size_t)g*4096 + tg;
    float dv = b2f(dl[rowo*256 + d]);
    float uv = b2f(uu[rowo*256 + d]);
    uint4 bv = *(const uint4*)(bc + rowo*16);
    float bn[8]; unpack8(bv, bn);
    float du = dv*uv;
    #pragma unroll
    for(int n=0;n<8;n++){
      float da = __expf(dv*An[n]);
      h[n] = fmaf(da, h[n], du*bn[n]);
      ap[n] *= da;
    }
  }
  size_t base = ((((size_t)dir*8+g)*128 + c)*256 + d)*8;
  *(float4*)(abuf+base)   = (float4){ap[0],ap[1],ap[2],ap[3]};
  *(float4*)(abuf+base+4) = (float4){ap[4],ap[5],ap[6],ap[7]};
  *(float4*)(bbuf+base)   = (float4){h[0],h[1],h[2],h[3]};
  *(float4*)(bbuf+base+4) = (float4){h[4],h[5],h[6],h[7]};
}

// ---------------- scan pass 2, 128 chunks, 512 blocks x 64 threads ----------------
__global__ void k_scan2(const float* __restrict__ abuf, const float* __restrict__ bbuf,
                        float* __restrict__ hs){
  int dblk = blockIdx.x, g = blockIdx.y, dir = blockIdx.z;
  int n = threadIdx.x & 7, dd = threadIdx.x >> 3;   // 64 threads: 8 d x 8 n
  int d = dblk*8 + dd;
  float h = 0.f;
  size_t gofs = (((size_t)dir*8+g)*128);
  #pragma unroll 4
  for(int c=0;c<128;c++){
    size_t idx = ((gofs + c)*256 + d)*8 + n;
    hs[idx] = h;
    h = fmaf(abuf[idx], h, bbuf[idx]);
  }
}

// ---------------- fused scanY + out_proj: bidirectional replay -> y in LDS A-tile -> GEMM + LN2 + residual (+ next LN1) ----------------
#define AP 264
template<int LAST>
__global__ __launch_bounds__(256)
void k_scanYO(const u16* __restrict__ df, const u16* __restrict__ db,
              const float* __restrict__ xf, const u16* __restrict__ zb,
              const u16* __restrict__ bcf, const u16* __restrict__ bcb,
              const u16* __restrict__ Alog, const u16* __restrict__ Ablog,
              const u16* __restrict__ Dp, const u16* __restrict__ cw, const u16* __restrict__ cb,
              const float* __restrict__ hs,
              const u16* __restrict__ Bw,
              float* __restrict__ X, u16* __restrict__ xnh,
              const u16* __restrict__ mnw, const u16* __restrict__ mnb,
              const u16* __restrict__ lnw_n, const u16* __restrict__ lnb_n,
              int layer){
  __shared__ char smem[32768 + AP*32*2];   // [0,32K): ybs (phase 1) / Bs (phase 2); [32K,+16.5K): As
  float* ybs = (float*)smem;
  u16*   Bsm = (u16*)smem;
  u16*   Asm = (u16*)(smem + 32768);
  __shared__ float red[4][32][2];
  int c = blockIdx.x, g = blockIdx.y, d = threadIdx.x;
  int l0 = c*32;
  float Dd = b2f(Dp[layer*256 + d]);
  float w0 = b2f(cw[(size_t)layer*1024 + d*4 + 0]);
  float w1 = b2f(cw[(size_t)layer*1024 + d*4 + 1]);
  float w2 = b2f(cw[(size_t)layer*1024 + d*4 + 2]);
  float w3 = b2f(cw[(size_t)layer*1024 + d*4 + 3]);
  float cbb = b2f(cb[layer*256 + d]);
  const float* xrow = xf + (size_t)g*4096*256 + d;
  const u16*  zrow = zb + (size_t)g*4096*256 + d;
  float An[8], h[8];
  // ---- bwd half (global bwd chunk 127-c), rows descending, pre-gate y -> ybs ----
  {
    #pragma unroll
    for(int n=0;n<8;n++) An[n] = -__expf(b2f(Ablog[(size_t)layer*2048 + d*8 + n]));
    size_t base = ((((size_t)8+g)*128 + (127-c))*256 + d)*8;
    float4 h0 = *(const float4*)(hs+base);
    float4 h1 = *(const float4*)(hs+base+4);
    h[0]=h0.x; h[1]=h0.y; h[2]=h0.z; h[3]=h0.w;
    h[4]=h1.x; h[5]=h1.y; h[6]=h1.z; h[7]=h1.w;
    float xw1 = (l0+32<4096) ? xrow[(size_t)(l0+32)*256] : 0.f;
    float xw2 = (l0+33<4096) ? xrow[(size_t)(l0+33)*256] : 0.f;
    float xw3 = (l0+34<4096) ? xrow[(size_t)(l0+34)*256] : 0.f;
    #pragma unroll 4
    for(int q=0;q<32;q++){
      int t = 31 - q;
      size_t rowo = (size_t)g*4096 + l0 + t;
      float x0 = xrow[(size_t)(l0+t)*256];
      float ucv = cbb + w3*x0 + w2*xw1 + w1*xw2 + w0*xw3;
      xw3 = xw2; xw2 = xw1; xw1 = x0;
      float uv = ucv / (1.f + __expf(-ucv));
      float dv = b2f(db[rowo*256 + d]);
      uint4 bv = *(const uint4*)(bcb + rowo*16);
      uint4 cv = *(const uint4*)(bcb + rowo*16 + 8);
      float bn[8], cn_[8];
      unpack8(bv, bn); unpack8(cv, cn_);
      float du = dv*uv;
      float y = 0.f;
      #pragma unroll
      for(int n=0;n<8;n++){
        float da = __expf(dv*An[n]);
        h[n] = fmaf(da, h[n], du*bn[n]);
        y = fmaf(h[n], cn_[n], y);
      }
      ybs[t*256 + d] = y + Dd*uv;
    }
  }
  // ---- fwd half, rows ascending; add y_bwd, gate, write bf16 into A-tile ----
  {
    #pragma unroll
    for(int n=0;n<8;n++) An[n] = -__expf(b2f(Alog[(size_t)layer*2048 + d*8 + n]));
    size_t base = (((size_t)g*128 + c)*256 + d)*8;
    float4 h0 = *(const float4*)(hs+base);
    float4 h1 = *(const float4*)(hs+base+4);
    h[0]=h0.x; h[1]=h0.y; h[2]=h0.z; h[3]=h0.w;
    h[4]=h1.x; h[5]=h1.y; h[6]=h1.z; h[7]=h1.w;
    float wm1 = (l0-1>=0) ? xrow[(size_t)(l0-1)*256] : 0.f;
    float wm2 = (l0-2>=0) ? xrow[(size_t)(l0-2)*256] : 0.f;
    float wm3 = (l0-3>=0) ? xrow[(size_t)(l0-3)*256] : 0.f;
    #pragma unroll 4
    for(int t=0;t<32;t++){
      size_t rowo = (size_t)g*4096 + l0 + t;
      float x0 = xrow[(size_t)(l0+t)*256];
      float ucv = cbb + w0*wm3 + w1*wm2 + w2*wm1 + w3*x0;
      wm3 = wm2; wm2 = wm1; wm1 = x0;
      float uv = ucv / (1.f + __expf(-ucv));
      float dv = b2f(df[rowo*256 + d]);
      uint4 bv = *(const uint4*)(bcf + rowo*16);
      uint4 cv = *(const uint4*)(bcf + rowo*16 + 8);
      float bn[8], cn_[8];
      unpack8(bv, bn); unpack8(cv, cn_);
      float du = dv*uv;
      float y = 0.f;
      #pragma unroll
      for(int n=0;n<8;n++){
        float da = __expf(dv*An[n]);
        h[n] = fmaf(da, h[n], du*bn[n]);
        y = fmaf(h[n], cn_[n], y);
      }
      y += Dd*uv;
      y += ybs[t*256 + d];
      float zv = b2f(zrow[(size_t)(l0+t)*256]);
      float yv = y * 0.5f * zv / (1.f + __expf(-zv));
      Asm[t*AP + d] = f2b(yv);
    }
  }
  __syncthreads();   // all ybs reads done; Bsm may now overwrite; Asm visible to all
  // ---- GEMM phase: A(32x256) @ Bw^T(256x256), 4 waves = 2(M) x 2(N) ----
  int wid = d>>6, lane = d&63;
  int mrow0 = (wid&1)*16, ncol0 = (wid>>1)*128;
  f32x4 acc[8];
  #pragma unroll
  for(int j=0;j<8;j++) acc[j] = (f32x4){0.f,0.f,0.f,0.f};
  int lrow = lane>>3;
  int scol = ((lane&7) ^ lrow) * 8;
  for(int k0=0;k0<256;k0+=64){
    #pragma unroll
    for(int it=0; it<8; ++it){
      int chunk = wid*8 + it;
      int row = chunk*8 + lrow;
      gl_lds16(Bw + (size_t)row*256 + k0 + scol, Bsm + chunk*512 + lane*8);
    }
    __syncthreads();
    #pragma unroll
    for(int kk=0;kk<2;kk++){
      int q  = kk*4 + (lane>>4);
      s16x8 af = *(const s16x8*)(Asm + (mrow0 + (lane&15))*AP + k0 + kk*32 + (lane>>4)*8);
      #pragma unroll
      for(int j=0;j<8;j++){
        int br = ncol0 + j*16 + (lane&15);
        s16x8 bfv = *(const s16x8*)(Bsm + br*64 + (q^(br&7))*8);
        acc[j] = __builtin_amdgcn_mfma_f32_16x16x32_bf16(af, bfv, acc[j], 0,0,0);
      }
    }
    __syncthreads();
  }
  // ---- epilogue: LN2 + residual (+ next-layer LN1) with cross-wave row stats ----
  size_t gm0 = (size_t)g*4096 + l0;
  int quad = lane>>4;
  float sm[4]={0,0,0,0}, sq[4]={0,0,0,0};
  #pragma unroll
  for(int j=0;j<8;j++)
    #pragma unroll
    for(int r=0;r<4;r++){ float v=acc[j][r]; sm[r]+=v; sq[r]+=v*v; }
  #pragma unroll
  for(int o=1;o<16;o<<=1)
    #pragma unroll
    for(int r=0;r<4;r++){ sm[r]+=__shfl_xor(sm[r],o); sq[r]+=__shfl_xor(sq[r],o); }
  if ((lane&15)==0){
    #pragma unroll
    for(int r=0;r<4;r++){ red[wid][quad*4+r][0]=sm[r]; red[wid][quad*4+r][1]=sq[r]; }
  }
  __syncthreads();
  float mu[4], rs[4];
  #pragma unroll
  for(int r=0;r<4;r++){
    float s2 = red[wid][quad*4+r][0] + red[wid^2][quad*4+r][0];
    float q2 = red[wid][quad*4+r][1] + red[wid^2][quad*4+r][1];
    mu[r] = s2*(1.f/256.f);
    float var = q2*(1.f/256.f) - mu[r]*mu[r];
    rs[r] = rsqrtf(var + 1e-5f);
  }
  #pragma unroll
  for(int j=0;j<8;j++){
    int col = ncol0 + j*16 + (lane&15);
    float w = b2f(mnw[col]), bb = b2f(mnb[col]);
    #pragma unroll
    for(int r=0;r<4;r++){
      size_t m = gm0 + mrow0 + quad*4 + r;
      float xn = X[m*256 + col] + (acc[j][r]-mu[r])*rs[r]*w + bb;
      X[m*256 + col] = xn;
      acc[j][r] = xn;
    }
  }
  if (!LAST){
    float sm2[4]={0,0,0,0}, sq2[4]={0,0,0,0};
    #pragma unroll
    for(int j=0;j<8;j++)
      #pragma unroll
      for(int r=0;r<4;r++){ float v=acc[j][r]; sm2[r]+=v; sq2[r]+=v*v; }
    #pragma unroll
    for(int o=1;o<16;o<<=1)
      #pragma unroll
      for(int r=0;r<4;r++){ sm2[r]+=__shfl_xor(sm2[r],o); sq2[r]+=__shfl_xor(sq2[r],o); }
    __syncthreads();   // protect red reuse
    if ((lane&15)==0){
      #pragma unroll
      for(int r=0;r<4;r++){ red[wid][quad*4+r][0]=sm2[r]; red[wid][quad*4+r][1]=sq2[r]; }
    }
    __syncthreads();
    float mu2[4], rs2[4];
    #pragma unroll
    for(int r=0;r<4;r++){
      float s2 = red[wid][quad*4+r][0] + red[wid^2][quad*4+r][0];
      float q2 = red[wid][quad*4+r][1] + red[wid^2][quad*4+r][1];
      mu2[r] = s2*(1.f/256.f);
      float var = q2*(1.f/256.f) - mu2[r]*mu2[r];
      rs2[r] = rsqrtf(var + 1e-5f);
    }
    #pragma unroll
    for(int j=0;j<8;j++){
      int col = ncol0 + j*16 + (lane&15);
      float w = b2f(lnw_n[col]), bb = b2f(lnb_n[col]);
      #pragma unroll
      for(int r=0;r<4;r++){
        size_t m = gm0 + mrow0 + quad*4 + r;
        float vv = (acc[j][r]-mu2[r])*rs2[r]*w + bb;
        xnh[m*256 + col] = f2b(vv);
      }
    }
  }
}

// ---------------- final transpose ----------------
__global__ void k_tr(const float* __restrict__ x, void* __restrict__ out, const int* __restrict__ flag){
  __shared__ float tile[32][129];
  int isbf = *flag;
  int l0 = blockIdx.x*128, c0 = blockIdx.y*32, g = blockIdx.z;
  int tid = threadIdx.x;
  for(int it=0; it<16; ++it){
    int idx = it*256 + tid;
    int lj = idx>>5, ci = idx&31;
    tile[ci][lj] = x[((size_t)g*4096 + l0+lj)*256 + c0+ci];
  }
  __syncthreads();
  for(int it=0; it<16; ++it){
    int idx = it*256 + tid;
    int lj = idx&127, ci = idx>>7;
    size_t o = ((size_t)g*256 + c0+ci)*4096 + l0+lj;
    float v = tile[ci][lj];
    if (isbf) ((u16*)out)[o] = f2b(v);
    else      ((float*)out)[o] = v;
  }
}

extern "C" void kernel_launch(void* const* d_in, const int* in_sizes, int n_in,
                              void* d_out, int out_size, void* d_ws, size_t ws_size,
                              hipStream_t stream){
  (void)in_sizes; (void)n_in; (void)out_size; (void)ws_size;
  const int* rl = (const int*)d_in[15];

  char* ws = (char*)d_ws;
  float* X    = (float*)(ws);                    // 32 MB fp32 residual
  float* XF   = (float*)(ws + 33554432);         // 32 MB fp32 x (g,l,256)
  u16*  ZB    = (u16*) (ws + 67108864);          // 16 MB bf16 z (g,l,256)
  u16*  XCF   = (u16*) (ws + 100663296);         // 16 MB (XCB contiguous after)
  u16*  XCB   = (u16*) (ws + 117440512);         // 16 MB
  u16*  DF    = (u16*) (ws + 134217728);         // 16 MB (DB contiguous after)
  u16*  DB    = (u16*) (ws + 150994944);         // 16 MB
  u16*  BCF   = (u16*) (ws + 167772160);         // 1 MB  (BCB contiguous after)
  u16*  BCB   = (u16*) (ws + 168820736);         // 1 MB
  u16*  BCOMB = (u16*) (ws + 169869312);         // 0.75 MB
  float* ABUF = (float*)(ws + 170655744);        // 16 MB } XNh aliases ABUF (lifetime-disjoint:
  u16*  XNh   = (u16*) (ws + 170655744);         //       } XNh read by gemm0 before scan1 writes ABUF)
  float* BBUF = (float*)(ws + 187432960);        // 16 MB
  float* HS   = (float*)(ws + 204210176);        // 16 MB
  u16*  WCVT  = (u16*) (ws + 220987392);         // ~1.73 MB canonical bf16 weights
  int*  FLAG  = (int*) (ws + 222715904);

  u16* W_lnw  = WCVT + 0;
  u16* W_lnb  = WCVT + 1024;
  u16* W_inp  = WCVT + 2048;
  u16* W_cw   = WCVT + 526336;
  u16* W_cb   = WCVT + 530432;
  u16* W_xp   = WCVT + 531456;
  u16* W_dtw  = WCVT + 564224;
  u16* W_dtb  = WCVT + 580608;
  u16* W_Al   = WCVT + 581632;
  u16* W_Abl  = WCVT + 589824;
  u16* W_D    = WCVT + 598016;
  u16* W_outp = WCVT + 599040;
  u16* W_mnw  = WCVT + 861184;
  u16* W_mnb  = WCVT + 862208;

  k_detect<<<1,64,0,stream>>>((const u16*)d_in[1], FLAG);

  CvtTable t;
  const int idxs[14] = {1,2,3,4,5,6,7,8,9,10,11,12,13,14};
  u16* dsts[14] = {W_lnw,W_lnb,W_inp,W_cw,W_cb,W_xp,W_dtw,W_dtb,W_Al,W_Abl,W_D,W_outp,W_mnw,W_mnb};
  const int ns[14] = {1024,1024,524288,4096,1024,32768,16384,1024,8192,8192,1024,262144,1024,1024};
  for(int i=0;i<14;i++){ t.src[i]=d_in[idxs[i]]; t.dst[i]=dsts[i]; t.n[i]=ns[i]; }
  k_cvt<<<dim3(32,14),256,0,stream>>>(t, FLAG);

  k_mean<<<dim3(32,8,8),256,0,stream>>>(d_in[0], rl, X, FLAG);
  k_prep<<<dim3(384,4),256,0,stream>>>(W_dtw, W_xp, BCOMB);
  k_ln1<<<8192,256,0,stream>>>(X, XNh, W_lnw, W_lnb, 0);

  for(int layer=0; layer<4; ++layer){
    k_gemm<0><<<dim3(256,4),256,0,stream>>>(XNh, W_inp + (size_t)layer*512*256,
                                            nullptr, XF, 256, nullptr, ZB);
    k_conv<<<dim3(128,8),256,0,stream>>>(XF, W_cw, W_cb, XCF, XCB, layer);
    k_gemm<1><<<dim3(512,3),256,0,stream>>>(XCF, BCOMB + (size_t)layer*384*256,
                                            DF, nullptr, 256, W_dtb + layer*256, BCF);
    k_scan1<<<dim3(128,8,2),256,0,stream>>>(DF,DB,XCF,XCB,BCF,BCB,W_Al,W_Abl,ABUF,BBUF,layer);
    k_scan2<<<dim3(32,8,2),64,0,stream>>>(ABUF,BBUF,HS);
    if (layer < 3){
      k_scanYO<0><<<dim3(128,8),256,0,stream>>>(DF,DB,XF,ZB,BCF,BCB,W_Al,W_Abl,W_D,W_cw,W_cb,HS,
                                                W_outp + (size_t)layer*256*256, X, XNh,
                                                W_mnw + layer*256, W_mnb + layer*256,
                                                W_lnw + (layer+1)*256, W_lnb + (layer+1)*256, layer);
    } else {
      k_scanYO<1><<<dim3(128,8),256,0,stream>>>(DF,DB,XF,ZB,BCF,BCB,W_Al,W_Abl,W_D,W_cw,W_cb,HS,
                                                W_outp + (size_t)layer*256*256, X, XNh,
                                                W_mnw + layer*256, W_mnb + layer*256,
                                                W_lnw, W_lnb, layer);
    }
  }
  k_tr<<<dim3(32,8,8),256,0,stream>>>(X, d_out, FLAG);
}